// Round 3
// baseline (357.479 us; speedup 1.0000x reference)
//
#include <hip/hip_runtime.h>
#include <float.h>

#define NBATCH 16384
// Largest magnitude that stays FINITE after fp32->bf16 RNE cast
#define SAFE_MAX 3.3e38f
#define SAFE_NEG -3.3e38f

typedef __attribute__((ext_vector_type(8))) short bf16x8;
typedef __attribute__((ext_vector_type(4))) float f32x4;

__device__ __forceinline__ float san(float v) {
    v = (v == v) ? v : 0.0f;                       // NaN -> 0
    return fminf(fmaxf(v, SAFE_NEG), SAFE_MAX);    // clamp: bf16-cast stays finite
}

__device__ __forceinline__ float tanh_fast(float a) {
    float e = __expf(a + a);
    return fmaf(-2.0f, __builtin_amdgcn_rcpf(e + 1.0f), 1.0f);
}

__device__ __forceinline__ unsigned short f2bf_rne(float v) {
    unsigned int u = __float_as_uint(v);
    return (unsigned short)((u + 0x7FFFu + ((u >> 16) & 1u)) >> 16);
}

// ==================== fused v3: v2 algorithm, spill-free register budget =====
// grid 512 x 512thr (8 waves), 2 blocks/CU -> 16 waves/CU, VGPR cap 128
// (v2's 1024-thr block capped VGPR at 64 -> 17 MB scratch spills = the 146us).
// Tile = 32 elements. Pool: wave w owns elements w*4..w*4+3; swapped MFMA
// D = W^T X^T puts H[.,l] in the register index -> in-register score reduce +
// softmax (proven v2 math, unchanged). Heads: pi on waves 0-3, value on waves
// 4-7, lane = (el = lane&31, h = lane>>5) covering 16 h-rows each.
extern "C" __global__ void __launch_bounds__(512, 4)
fused_v3(const float* __restrict__ X, const float* __restrict__ LM,
         const float* __restrict__ AM,
         const float* __restrict__ W, const float* __restrict__ bW,
         const float* __restrict__ vv,
         const float* __restrict__ projW, const float* __restrict__ projb,
         const float* __restrict__ piW1, const float* __restrict__ pib1,
         const float* __restrict__ piW2, const float* __restrict__ pib2,
         const float* __restrict__ piW3, const float* __restrict__ pib3,
         const float* __restrict__ vfW1, const float* __restrict__ vfb1,
         const float* __restrict__ vfW2, const float* __restrict__ vfb2,
         const float* __restrict__ vfW3, const float* __restrict__ vfb3,
         float* __restrict__ out)
{
    __shared__ __align__(16) short wt[32 * 40];   // W^T bf16 [n=g][k=f], stride 40
    __shared__ float zl[64 * 33];                 // z[zdim][elem], stride 33
    __shared__ float pool_s[8][32];               // per-wave pooled
    __shared__ float h1pi[128 * 32];              // pi hidden1 (16 KB)
    __shared__ float h1v[128 * 32];               // value hidden1 (16 KB)
    __shared__ float plpi[8 * 256];               // pi layer-3 partials (8 KB)
    __shared__ float plv[32 * 8];                 // value partials (1 KB)

    const int tid  = threadIdx.x;
    const int w    = __builtin_amdgcn_readfirstlane(tid >> 6);
    const int lane = tid & 63;
    const int c    = lane & 15;
    const int quad = lane >> 4;
    const long btile = (long)blockIdx.x * 32;

    // ---- stage W^T bf16 ----
    for (int i = tid; i < 1024; i += 512) {
        const int n = i >> 5, k = i & 31;
        wt[n * 40 + k] = (short)f2bf_rne(W[k * 32 + n]);
    }

    // per-lane bias/v for g = 16u + 4*quad + r  (register-resident)
    float bwr[8], vvr[8];
#pragma unroll
    for (int u = 0; u < 2; ++u)
#pragma unroll
        for (int r = 0; r < 4; ++r) {
            const int g = 16 * u + 4 * quad + r;
            bwr[u * 4 + r] = bW[g];
            vvr[u * 4 + r] = vv[g];
        }
    const float pjb = projb[lane];

    __syncthreads();   // wt visible

    // W^T A-frags: lane holds A[m=g=16u+c][k=quad*8..+8] (resident all pool)
    union { bf16x8 v; uint4 q; } bfr[2];
#pragma unroll
    for (int u = 0; u < 2; ++u)
        bfr[u].q = *((const uint4*)&wt[(16 * u + c) * 40 + quad * 8]);

    // ==================== pool phase: 4 elements per wave ====================
#pragma unroll 1
    for (int it = 0; it < 4; ++it) {
        const int brel = w * 4 + it;
        const long b = btile + brel;

        // X rows l=16t+c, k-slice quad*8..+8 (fp32 kept for pooling)
        float xr[4][8];
#pragma unroll
        for (int t = 0; t < 4; ++t) {
            const float4* p = (const float4*)(X + b * 2048 + (16 * t + c) * 32 + quad * 8);
            float4 a0 = p[0], a1 = p[1];
            xr[t][0] = a0.x; xr[t][1] = a0.y; xr[t][2] = a0.z; xr[t][3] = a0.w;
            xr[t][4] = a1.x; xr[t][5] = a1.y; xr[t][6] = a1.z; xr[t][7] = a1.w;
        }
        // masks for this lane's 4 rows l = 16t+c
        float ml[4];
#pragma unroll
        for (int t = 0; t < 4; ++t) ml[t] = LM[b * 64 + 16 * t + c];

        // pack X B-frags (bf16 truncation via v_perm — proven pack)
        union { bf16x8 v; unsigned int u[4]; } afr[4];
#pragma unroll
        for (int t = 0; t < 4; ++t)
#pragma unroll
            for (int j2 = 0; j2 < 4; ++j2)
                afr[t].u[j2] = __builtin_amdgcn_perm(
                    __float_as_uint(xr[t][2 * j2 + 1]),
                    __float_as_uint(xr[t][2 * j2]), 0x07060302u);

        // swapped MFMA: D[g,l] = sum_f W[f,g] X[l,f]; u-tiles sequential.
        float sp[4] = {0.f, 0.f, 0.f, 0.f};
#pragma unroll
        for (int u = 0; u < 2; ++u) {
            f32x4 a[4];
#pragma unroll
            for (int t = 0; t < 4; ++t) {
                a[t] = (f32x4){0.f, 0.f, 0.f, 0.f};
                a[t] = __builtin_amdgcn_mfma_f32_16x16x32_bf16(
                    bfr[u].v, afr[t].v, a[t], 0, 0, 0);
            }
#pragma unroll
            for (int t = 0; t < 4; ++t)
#pragma unroll
                for (int r = 0; r < 4; ++r)
                    sp[t] = fmaf(tanh_fast(a[t][r] + bwr[u * 4 + r]),
                                 vvr[u * 4 + r], sp[t]);
        }

        // quad butterfly: all lanes get full score for their l=16t+c
        float s[4];
#pragma unroll
        for (int t = 0; t < 4; ++t) {
            float v0 = sp[t];
            v0 += __shfl_xor(v0, 16);
            v0 += __shfl_xor(v0, 32);
            s[t] = v0;
        }

        // in-register masked softmax over all 64 rows
        bool act[4];
#pragma unroll
        for (int t = 0; t < 4; ++t) act[t] = ml[t] > 0.5f;

        float m = -1e30f;
#pragma unroll
        for (int t = 0; t < 4; ++t) m = fmaxf(m, act[t] ? s[t] : -1e30f);
        m = fmaxf(m, __shfl_xor(m, 1));
        m = fmaxf(m, __shfl_xor(m, 2));
        m = fmaxf(m, __shfl_xor(m, 4));
        m = fmaxf(m, __shfl_xor(m, 8));

        float ev[4];
        float es = 0.0f;
#pragma unroll
        for (int t = 0; t < 4; ++t) {
            ev[t] = act[t] ? __expf(s[t] - m) : 0.0f;
            es += ev[t];
        }
        es += __shfl_xor(es, 1);
        es += __shfl_xor(es, 2);
        es += __shfl_xor(es, 4);
        es += __shfl_xor(es, 8);
        const float rcpS = __builtin_amdgcn_rcpf(es);

        float wgt[4];
#pragma unroll
        for (int t = 0; t < 4; ++t)
            wgt[t] = (act[t] && es > 0.0f) ? ev[t] * rcpS : 0.0f;

        // pooled[quad*8+j] = sum_l wgt[l]*X[l,f] : 4 FMA + c-butterfly per j
#pragma unroll
        for (int j = 0; j < 8; ++j) {
            float p = wgt[0] * xr[0][j];
#pragma unroll
            for (int t = 1; t < 4; ++t) p = fmaf(wgt[t], xr[t][j], p);
            p += __shfl_xor(p, 1);
            p += __shfl_xor(p, 2);
            p += __shfl_xor(p, 4);
            p += __shfl_xor(p, 8);
            if (c == 0) pool_s[w][quad * 8 + j] = p;
        }
        // wave-private buffer: drain DS queue (no block barrier needed)
        asm volatile("s_waitcnt lgkmcnt(0)" ::: "memory");

        // z[e] = pooled . projW[:,e] + projb[e]  (lane = e) -> LDS
        float zv = pjb;
#pragma unroll
        for (int f = 0; f < 32; ++f)
            zv = fmaf(pool_s[w][f], projW[f * 64 + lane], zv);
        const bool anyl = act[0] | act[1] | act[2] | act[3];
        const bool any = (__ballot(anyl) != 0ull);
        zl[lane * 33 + brel] = any ? san(zv) : 0.0f;
    }
    __syncthreads();   // z tile visible to all waves

    // ============ heads: pi on waves 0-3, value on waves 4-7 (concurrent) ====
    const int el = lane & 31;          // element in tile
    const int hh = lane >> 5;          // half: which 16-row group
    const int w4 = w - 4;

    // ---- phase 1: layer 1 (each lane computes 16 h1 rows for its element) ----
    if (w < 4) {
        const int rb0 = w * 32 + hh * 16;
        float acc[16];
#pragma unroll
        for (int i = 0; i < 16; ++i) acc[i] = pib1[rb0 + i];
#pragma unroll 8
        for (int e = 0; e < 64; ++e) {
            const float zv = zl[e * 33 + el];
            const float* wr = piW1 + e * 128 + rb0;
#pragma unroll
            for (int i = 0; i < 16; ++i) acc[i] = fmaf(zv, wr[i], acc[i]);
        }
#pragma unroll
        for (int i = 0; i < 16; ++i)
            h1pi[(rb0 + i) * 32 + el] = tanh_fast(acc[i]);
    } else {
        const int rb0 = w4 * 32 + hh * 16;
        float acc[16];
#pragma unroll
        for (int i = 0; i < 16; ++i) acc[i] = vfb1[rb0 + i];
#pragma unroll 8
        for (int e = 0; e < 64; ++e) {
            const float zv = zl[e * 33 + el];
            const float* wr = vfW1 + e * 128 + rb0;
#pragma unroll
            for (int i = 0; i < 16; ++i) acc[i] = fmaf(zv, wr[i], acc[i]);
        }
#pragma unroll
        for (int i = 0; i < 16; ++i)
            h1v[(rb0 + i) * 32 + el] = tanh_fast(acc[i]);
    }
    __syncthreads();

    // ---- phase 2: layer 2 + layer 3 partials ----
    if (w < 4) {
        const int rb0 = w * 32 + hh * 16;
        const int g   = w * 2 + hh;
        float a2[16];
#pragma unroll
        for (int i = 0; i < 16; ++i) a2[i] = pib2[rb0 + i];
#pragma unroll 8
        for (int j = 0; j < 128; ++j) {
            const float hv = h1pi[j * 32 + el];
            const float* wr = piW2 + j * 128 + rb0;
#pragma unroll
            for (int i = 0; i < 16; ++i) a2[i] = fmaf(hv, wr[i], a2[i]);
        }
        float pl[8];
#pragma unroll
        for (int a = 0; a < 8; ++a) pl[a] = 0.0f;
#pragma unroll
        for (int i = 0; i < 16; ++i) {
            const float h2 = tanh_fast(a2[i]);
            const float* wr = piW3 + (rb0 + i) * 8;
#pragma unroll
            for (int a = 0; a < 8; ++a) pl[a] = fmaf(h2, wr[a], pl[a]);
        }
#pragma unroll
        for (int a = 0; a < 8; ++a)
            plpi[g * 256 + el * 8 + a] = pl[a];
    } else {
        const int rb0 = w4 * 32 + hh * 16;
        const int g   = w4 * 2 + hh;
        float a2[16];
#pragma unroll
        for (int i = 0; i < 16; ++i) a2[i] = vfb2[rb0 + i];
#pragma unroll 8
        for (int j = 0; j < 128; ++j) {
            const float hv = h1v[j * 32 + el];
            const float* wr = vfW2 + j * 128 + rb0;
#pragma unroll
            for (int i = 0; i < 16; ++i) a2[i] = fmaf(hv, wr[i], a2[i]);
        }
        float pv = 0.0f;
#pragma unroll
        for (int i = 0; i < 16; ++i)
            pv = fmaf(tanh_fast(a2[i]), vfW3[rb0 + i], pv);
        plv[el * 8 + g] = pv;
    }
    __syncthreads();

    // ---- phase 3: final reductions + stores ----
    if (w < 4) {
        // threads 0..255: rel = element in tile, ra = action
        const int rel = tid >> 3, ra = tid & 7;
        float lg = pib3[ra];
#pragma unroll
        for (int g2 = 0; g2 < 8; ++g2)
            lg += plpi[g2 * 256 + rel * 8 + ra];
        lg = san(lg);
        const long rb = btile + rel;
        const float am = AM[rb * 8 + ra];
        const bool inv = (am <= 0.0f);
        const unsigned long long bal = __ballot(inv);
        const int grp = (tid & 63) >> 3;
        const bool allinv = (((bal >> (grp * 8)) & 0xFFull) == 0xFFull);
        out[rb * 8 + ra] = allinv ? lg : (inv ? SAFE_NEG : lg);
    } else if (w == 4) {
        if (lane < 32) {
            float val = vfb3[0];
#pragma unroll
            for (int g2 = 0; g2 < 8; ++g2) val += plv[lane * 8 + g2];
            out[(long)NBATCH * 8 + btile + lane] = san(val);
        }
    }
}

// ---------------- launcher ----------------
extern "C" void kernel_launch(void* const* d_in, const int* in_sizes, int n_in,
                              void* d_out, int out_size, void* d_ws, size_t ws_size,
                              hipStream_t stream) {
    const float* X     = (const float*)d_in[0];
    const float* LM    = (const float*)d_in[1];
    const float* AM    = (const float*)d_in[2];
    const float* W     = (const float*)d_in[3];
    const float* bW    = (const float*)d_in[4];
    const float* vv    = (const float*)d_in[5];
    const float* projW = (const float*)d_in[6];
    const float* projb = (const float*)d_in[7];
    const float* piW1  = (const float*)d_in[8];
    const float* pib1  = (const float*)d_in[9];
    const float* piW2  = (const float*)d_in[10];
    const float* pib2  = (const float*)d_in[11];
    const float* piW3  = (const float*)d_in[12];
    const float* pib3  = (const float*)d_in[13];
    const float* vfW1  = (const float*)d_in[14];
    const float* vfb1  = (const float*)d_in[15];
    const float* vfW2  = (const float*)d_in[16];
    const float* vfb2  = (const float*)d_in[17];
    const float* vfW3  = (const float*)d_in[18];
    const float* vfb3  = (const float*)d_in[19];

    float* outp = (float*)d_out;

    fused_v3<<<NBATCH / 32, 512, 0, stream>>>(
        X, LM, AM, W, bW, vv, projW, projb,
        piW1, pib1, piW2, pib2, piW3, pib3,
        vfW1, vfb1, vfW2, vfb2, vfW3, vfb3, outp);
}

// Round 4
// 331.231 us; speedup vs baseline: 1.0792x; 1.0792x over previous
//
#include <hip/hip_runtime.h>
#include <float.h>

#define NBATCH 16384
// Largest magnitude that stays FINITE after fp32->bf16 RNE cast
#define SAFE_MAX 3.3e38f
#define SAFE_NEG -3.3e38f

typedef __attribute__((ext_vector_type(8))) short bf16x8;
typedef __attribute__((ext_vector_type(4))) float f32x4;

__device__ __forceinline__ float san(float v) {
    v = (v == v) ? v : 0.0f;                       // NaN -> 0
    return fminf(fmaxf(v, SAFE_NEG), SAFE_MAX);    // clamp: bf16-cast stays finite
}

__device__ __forceinline__ float tanh_fast(float a) {
    float e = __expf(a + a);
    return fmaf(-2.0f, __builtin_amdgcn_rcpf(e + 1.0f), 1.0f);
}

__device__ __forceinline__ unsigned short f2bf_rne(float v) {
    unsigned int u = __float_as_uint(v);
    return (unsigned short)((u + 0x7FFFu + ((u >> 16) & 1u)) >> 16);
}

// ==================== fused v4: v3 algorithm, launch_bounds(512,2) ===========
// Empirical VGPR series: (512,2)->104 no spill; (512,4)/(1024,4)->64 + MB-scale
// scratch spills (WRITE_SIZE 18-24 MB). On this toolchain the 2nd bounds arg
// acts CUDA-style (min blocks/CU): 4 -> 8 waves/SIMD -> 64-VGPR cap -> spills
// inside the pool chain. (512,2) caps at 256; allocator lands ~104, which
// still allows 4 waves/SIMD = 16 waves/CU with grid 512 (2 blocks/CU, 54 KB
// LDS x2 fits). Algorithm identical to v3: swapped MFMA D = W^T X^T puts
// H[.,l] in the register index -> in-register score reduce + softmax; heads
// pi on waves 0-3, value on waves 4-7, concurrent.
extern "C" __global__ void __launch_bounds__(512, 2)
fused_v4(const float* __restrict__ X, const float* __restrict__ LM,
         const float* __restrict__ AM,
         const float* __restrict__ W, const float* __restrict__ bW,
         const float* __restrict__ vv,
         const float* __restrict__ projW, const float* __restrict__ projb,
         const float* __restrict__ piW1, const float* __restrict__ pib1,
         const float* __restrict__ piW2, const float* __restrict__ pib2,
         const float* __restrict__ piW3, const float* __restrict__ pib3,
         const float* __restrict__ vfW1, const float* __restrict__ vfb1,
         const float* __restrict__ vfW2, const float* __restrict__ vfb2,
         const float* __restrict__ vfW3, const float* __restrict__ vfb3,
         float* __restrict__ out)
{
    __shared__ __align__(16) short wt[32 * 40];   // W^T bf16 [n=g][k=f], stride 40
    __shared__ float zl[64 * 33];                 // z[zdim][elem], stride 33
    __shared__ float pool_s[8][32];               // per-wave pooled
    __shared__ float h1pi[128 * 32];              // pi hidden1 (16 KB)
    __shared__ float h1v[128 * 32];               // value hidden1 (16 KB)
    __shared__ float plpi[8 * 256];               // pi layer-3 partials (8 KB)
    __shared__ float plv[32 * 8];                 // value partials (1 KB)

    const int tid  = threadIdx.x;
    const int w    = __builtin_amdgcn_readfirstlane(tid >> 6);
    const int lane = tid & 63;
    const int c    = lane & 15;
    const int quad = lane >> 4;
    const long btile = (long)blockIdx.x * 32;

    // ---- stage W^T bf16 ----
    for (int i = tid; i < 1024; i += 512) {
        const int n = i >> 5, k = i & 31;
        wt[n * 40 + k] = (short)f2bf_rne(W[k * 32 + n]);
    }

    // per-lane bias/v for g = 16u + 4*quad + r  (register-resident)
    float bwr[8], vvr[8];
#pragma unroll
    for (int u = 0; u < 2; ++u)
#pragma unroll
        for (int r = 0; r < 4; ++r) {
            const int g = 16 * u + 4 * quad + r;
            bwr[u * 4 + r] = bW[g];
            vvr[u * 4 + r] = vv[g];
        }
    const float pjb = projb[lane];

    __syncthreads();   // wt visible

    // W^T A-frags: lane holds A[m=g=16u+c][k=quad*8..+8] (resident all pool)
    union { bf16x8 v; uint4 q; } bfr[2];
#pragma unroll
    for (int u = 0; u < 2; ++u)
        bfr[u].q = *((const uint4*)&wt[(16 * u + c) * 40 + quad * 8]);

    // ==================== pool phase: 4 elements per wave ====================
#pragma unroll 1
    for (int it = 0; it < 4; ++it) {
        const int brel = w * 4 + it;
        const long b = btile + brel;

        // X rows l=16t+c, k-slice quad*8..+8 (fp32 kept for pooling)
        float xr[4][8];
#pragma unroll
        for (int t = 0; t < 4; ++t) {
            const float4* p = (const float4*)(X + b * 2048 + (16 * t + c) * 32 + quad * 8);
            float4 a0 = p[0], a1 = p[1];
            xr[t][0] = a0.x; xr[t][1] = a0.y; xr[t][2] = a0.z; xr[t][3] = a0.w;
            xr[t][4] = a1.x; xr[t][5] = a1.y; xr[t][6] = a1.z; xr[t][7] = a1.w;
        }
        // masks for this lane's 4 rows l = 16t+c
        float ml[4];
#pragma unroll
        for (int t = 0; t < 4; ++t) ml[t] = LM[b * 64 + 16 * t + c];

        // pack X B-frags (bf16 truncation via v_perm — proven pack)
        union { bf16x8 v; unsigned int u[4]; } afr[4];
#pragma unroll
        for (int t = 0; t < 4; ++t)
#pragma unroll
            for (int j2 = 0; j2 < 4; ++j2)
                afr[t].u[j2] = __builtin_amdgcn_perm(
                    __float_as_uint(xr[t][2 * j2 + 1]),
                    __float_as_uint(xr[t][2 * j2]), 0x07060302u);

        // swapped MFMA: D[g,l] = sum_f W[f,g] X[l,f]; u-tiles sequential.
        float sp[4] = {0.f, 0.f, 0.f, 0.f};
#pragma unroll
        for (int u = 0; u < 2; ++u) {
            f32x4 a[4];
#pragma unroll
            for (int t = 0; t < 4; ++t) {
                a[t] = (f32x4){0.f, 0.f, 0.f, 0.f};
                a[t] = __builtin_amdgcn_mfma_f32_16x16x32_bf16(
                    bfr[u].v, afr[t].v, a[t], 0, 0, 0);
            }
#pragma unroll
            for (int t = 0; t < 4; ++t)
#pragma unroll
                for (int r = 0; r < 4; ++r)
                    sp[t] = fmaf(tanh_fast(a[t][r] + bwr[u * 4 + r]),
                                 vvr[u * 4 + r], sp[t]);
        }

        // quad butterfly: all lanes get full score for their l=16t+c
        float s[4];
#pragma unroll
        for (int t = 0; t < 4; ++t) {
            float v0 = sp[t];
            v0 += __shfl_xor(v0, 16);
            v0 += __shfl_xor(v0, 32);
            s[t] = v0;
        }

        // in-register masked softmax over all 64 rows
        bool act[4];
#pragma unroll
        for (int t = 0; t < 4; ++t) act[t] = ml[t] > 0.5f;

        float m = -1e30f;
#pragma unroll
        for (int t = 0; t < 4; ++t) m = fmaxf(m, act[t] ? s[t] : -1e30f);
        m = fmaxf(m, __shfl_xor(m, 1));
        m = fmaxf(m, __shfl_xor(m, 2));
        m = fmaxf(m, __shfl_xor(m, 4));
        m = fmaxf(m, __shfl_xor(m, 8));

        float ev[4];
        float es = 0.0f;
#pragma unroll
        for (int t = 0; t < 4; ++t) {
            ev[t] = act[t] ? __expf(s[t] - m) : 0.0f;
            es += ev[t];
        }
        es += __shfl_xor(es, 1);
        es += __shfl_xor(es, 2);
        es += __shfl_xor(es, 4);
        es += __shfl_xor(es, 8);
        const float rcpS = __builtin_amdgcn_rcpf(es);

        float wgt[4];
#pragma unroll
        for (int t = 0; t < 4; ++t)
            wgt[t] = (act[t] && es > 0.0f) ? ev[t] * rcpS : 0.0f;

        // pooled[quad*8+j] = sum_l wgt[l]*X[l,f] : 4 FMA + c-butterfly per j
#pragma unroll
        for (int j = 0; j < 8; ++j) {
            float p = wgt[0] * xr[0][j];
#pragma unroll
            for (int t = 1; t < 4; ++t) p = fmaf(wgt[t], xr[t][j], p);
            p += __shfl_xor(p, 1);
            p += __shfl_xor(p, 2);
            p += __shfl_xor(p, 4);
            p += __shfl_xor(p, 8);
            if (c == 0) pool_s[w][quad * 8 + j] = p;
        }
        // wave-private buffer: drain DS queue (no block barrier needed)
        asm volatile("s_waitcnt lgkmcnt(0)" ::: "memory");

        // z[e] = pooled . projW[:,e] + projb[e]  (lane = e) -> LDS
        float zv = pjb;
#pragma unroll
        for (int f = 0; f < 32; ++f)
            zv = fmaf(pool_s[w][f], projW[f * 64 + lane], zv);
        const bool anyl = act[0] | act[1] | act[2] | act[3];
        const bool any = (__ballot(anyl) != 0ull);
        zl[lane * 33 + brel] = any ? san(zv) : 0.0f;
    }
    __syncthreads();   // z tile visible to all waves

    // ============ heads: pi on waves 0-3, value on waves 4-7 (concurrent) ====
    const int el = lane & 31;          // element in tile
    const int hh = lane >> 5;          // half: which 16-row group
    const int w4 = w - 4;

    // ---- phase 1: layer 1 (each lane computes 16 h1 rows for its element) ----
    if (w < 4) {
        const int rb0 = w * 32 + hh * 16;
        float acc[16];
#pragma unroll
        for (int i = 0; i < 16; ++i) acc[i] = pib1[rb0 + i];
#pragma unroll 8
        for (int e = 0; e < 64; ++e) {
            const float zv = zl[e * 33 + el];
            const float* wr = piW1 + e * 128 + rb0;
#pragma unroll
            for (int i = 0; i < 16; ++i) acc[i] = fmaf(zv, wr[i], acc[i]);
        }
#pragma unroll
        for (int i = 0; i < 16; ++i)
            h1pi[(rb0 + i) * 32 + el] = tanh_fast(acc[i]);
    } else {
        const int rb0 = w4 * 32 + hh * 16;
        float acc[16];
#pragma unroll
        for (int i = 0; i < 16; ++i) acc[i] = vfb1[rb0 + i];
#pragma unroll 8
        for (int e = 0; e < 64; ++e) {
            const float zv = zl[e * 33 + el];
            const float* wr = vfW1 + e * 128 + rb0;
#pragma unroll
            for (int i = 0; i < 16; ++i) acc[i] = fmaf(zv, wr[i], acc[i]);
        }
#pragma unroll
        for (int i = 0; i < 16; ++i)
            h1v[(rb0 + i) * 32 + el] = tanh_fast(acc[i]);
    }
    __syncthreads();

    // ---- phase 2: layer 2 + layer 3 partials ----
    if (w < 4) {
        const int rb0 = w * 32 + hh * 16;
        const int g   = w * 2 + hh;
        float a2[16];
#pragma unroll
        for (int i = 0; i < 16; ++i) a2[i] = pib2[rb0 + i];
#pragma unroll 8
        for (int j = 0; j < 128; ++j) {
            const float hv = h1pi[j * 32 + el];
            const float* wr = piW2 + j * 128 + rb0;
#pragma unroll
            for (int i = 0; i < 16; ++i) a2[i] = fmaf(hv, wr[i], a2[i]);
        }
        float pl[8];
#pragma unroll
        for (int a = 0; a < 8; ++a) pl[a] = 0.0f;
#pragma unroll
        for (int i = 0; i < 16; ++i) {
            const float h2 = tanh_fast(a2[i]);
            const float* wr = piW3 + (rb0 + i) * 8;
#pragma unroll
            for (int a = 0; a < 8; ++a) pl[a] = fmaf(h2, wr[a], pl[a]);
        }
#pragma unroll
        for (int a = 0; a < 8; ++a)
            plpi[g * 256 + el * 8 + a] = pl[a];
    } else {
        const int rb0 = w4 * 32 + hh * 16;
        const int g   = w4 * 2 + hh;
        float a2[16];
#pragma unroll
        for (int i = 0; i < 16; ++i) a2[i] = vfb2[rb0 + i];
#pragma unroll 8
        for (int j = 0; j < 128; ++j) {
            const float hv = h1v[j * 32 + el];
            const float* wr = vfW2 + j * 128 + rb0;
#pragma unroll
            for (int i = 0; i < 16; ++i) a2[i] = fmaf(hv, wr[i], a2[i]);
        }
        float pv = 0.0f;
#pragma unroll
        for (int i = 0; i < 16; ++i)
            pv = fmaf(tanh_fast(a2[i]), vfW3[rb0 + i], pv);
        plv[el * 8 + g] = pv;
    }
    __syncthreads();

    // ---- phase 3: final reductions + stores ----
    if (w < 4) {
        // threads 0..255: rel = element in tile, ra = action
        const int rel = tid >> 3, ra = tid & 7;
        float lg = pib3[ra];
#pragma unroll
        for (int g2 = 0; g2 < 8; ++g2)
            lg += plpi[g2 * 256 + rel * 8 + ra];
        lg = san(lg);
        const long rb = btile + rel;
        const float am = AM[rb * 8 + ra];
        const bool inv = (am <= 0.0f);
        const unsigned long long bal = __ballot(inv);
        const int grp = (tid & 63) >> 3;
        const bool allinv = (((bal >> (grp * 8)) & 0xFFull) == 0xFFull);
        out[rb * 8 + ra] = allinv ? lg : (inv ? SAFE_NEG : lg);
    } else if (w == 4) {
        if (lane < 32) {
            float val = vfb3[0];
#pragma unroll
            for (int g2 = 0; g2 < 8; ++g2) val += plv[lane * 8 + g2];
            out[(long)NBATCH * 8 + btile + lane] = san(val);
        }
    }
}

// ---------------- launcher ----------------
extern "C" void kernel_launch(void* const* d_in, const int* in_sizes, int n_in,
                              void* d_out, int out_size, void* d_ws, size_t ws_size,
                              hipStream_t stream) {
    const float* X     = (const float*)d_in[0];
    const float* LM    = (const float*)d_in[1];
    const float* AM    = (const float*)d_in[2];
    const float* W     = (const float*)d_in[3];
    const float* bW    = (const float*)d_in[4];
    const float* vv    = (const float*)d_in[5];
    const float* projW = (const float*)d_in[6];
    const float* projb = (const float*)d_in[7];
    const float* piW1  = (const float*)d_in[8];
    const float* pib1  = (const float*)d_in[9];
    const float* piW2  = (const float*)d_in[10];
    const float* pib2  = (const float*)d_in[11];
    const float* piW3  = (const float*)d_in[12];
    const float* pib3  = (const float*)d_in[13];
    const float* vfW1  = (const float*)d_in[14];
    const float* vfb1  = (const float*)d_in[15];
    const float* vfW2  = (const float*)d_in[16];
    const float* vfb2  = (const float*)d_in[17];
    const float* vfW3  = (const float*)d_in[18];
    const float* vfb3  = (const float*)d_in[19];

    float* outp = (float*)d_out;

    fused_v4<<<NBATCH / 32, 512, 0, stream>>>(
        X, LM, AM, W, bW, vv, projW, projb,
        piW1, pib1, piW2, pib2, piW3, pib3,
        vfW1, vfb1, vfW2, vfb2, vfW3, vfb3, outp);
}

// Round 5
// 257.003 us; speedup vs baseline: 1.3910x; 1.2888x over previous
//
#include <hip/hip_runtime.h>
#include <float.h>

#define NBATCH 16384
// Largest magnitude that stays FINITE after fp32->bf16 RNE cast
#define SAFE_MAX 3.3e38f
#define SAFE_NEG -3.3e38f

typedef __attribute__((ext_vector_type(8))) short bf16x8;
typedef __attribute__((ext_vector_type(4))) float f32x4;

__device__ __forceinline__ float san(float v) {
    v = (v == v) ? v : 0.0f;                       // NaN -> 0
    return fminf(fmaxf(v, SAFE_NEG), SAFE_MAX);    // clamp: bf16-cast stays finite
}

__device__ __forceinline__ float tanh_fast(float a) {
    float e = __expf(a + a);
    return fmaf(-2.0f, __builtin_amdgcn_rcpf(e + 1.0f), 1.0f);
}

__device__ __forceinline__ unsigned short f2bf_rne(float v) {
    unsigned int u = __float_as_uint(v);
    return (unsigned short)((u + 0x7FFFu + ((u >> 16) & 1u)) >> 16);
}

// ==================== pool v5: split, 1 elem/wave, short chain ===============
// R0's winning shape (grid 4096 x 256thr, (256,4) -> 104 VGPR, 16 waves/CU,
// ~4 chain-rounds) + v4's proven shorter per-element math: swapped MFMA
// D = W^T X^T puts H[.,l] in the REGISTER index -> score reduce = 8 reg-FMA +
// 2 shuffles, softmax fully in registers. Deletes R0-pool's sc/mk LDS
// round-trip and both per-element __syncthreads (waves drift after staging).
extern "C" __global__ void __launch_bounds__(256, 4)
pool_v5(const float* __restrict__ X, const float* __restrict__ LM,
        const float* __restrict__ W, const float* __restrict__ bW,
        const float* __restrict__ vv,
        const float* __restrict__ projW, const float* __restrict__ projb,
        float* __restrict__ zout)
{
    __shared__ __align__(16) short wt[32 * 40];   // W^T bf16 [n=g][k=f], stride 40
    __shared__ float pool_s[4][32];               // per-wave pooled

    const int tid  = threadIdx.x;
    const int w    = __builtin_amdgcn_readfirstlane(tid >> 6);
    const int lane = tid & 63;
    const int c    = lane & 15;
    const int quad = lane >> 4;
    const long b   = (long)blockIdx.x * 4 + w;

    // ---- stage W^T bf16 (once per block) ----
    for (int i = tid; i < 1024; i += 256) {
        const int n = i >> 5, k = i & 31;
        wt[n * 40 + k] = (short)f2bf_rne(W[k * 32 + n]);
    }

    // per-lane bias/v for g = 16u + 4*quad + r  (register-resident)
    float bwr[8], vvr[8];
#pragma unroll
    for (int u = 0; u < 2; ++u)
#pragma unroll
        for (int r = 0; r < 4; ++r) {
            const int g = 16 * u + 4 * quad + r;
            bwr[u * 4 + r] = bW[g];
            vvr[u * 4 + r] = vv[g];
        }
    const float pjb = projb[lane];

    // X rows l=16t+c, k-slice quad*8..+8 (fp32 kept for pooling)
    float xr[4][8];
#pragma unroll
    for (int t = 0; t < 4; ++t) {
        const float4* p = (const float4*)(X + b * 2048 + (16 * t + c) * 32 + quad * 8);
        float4 a0 = p[0], a1 = p[1];
        xr[t][0] = a0.x; xr[t][1] = a0.y; xr[t][2] = a0.z; xr[t][3] = a0.w;
        xr[t][4] = a1.x; xr[t][5] = a1.y; xr[t][6] = a1.z; xr[t][7] = a1.w;
    }
    // masks for this lane's 4 rows l = 16t+c
    float ml[4];
#pragma unroll
    for (int t = 0; t < 4; ++t) ml[t] = LM[b * 64 + 16 * t + c];

    // pack X B-frags (bf16 truncation via v_perm — proven pack)
    union { bf16x8 v; unsigned int u[4]; } afr[4];
#pragma unroll
    for (int t = 0; t < 4; ++t)
#pragma unroll
        for (int j2 = 0; j2 < 4; ++j2)
            afr[t].u[j2] = __builtin_amdgcn_perm(
                __float_as_uint(xr[t][2 * j2 + 1]),
                __float_as_uint(xr[t][2 * j2]), 0x07060302u);

    __syncthreads();   // wt visible (only barrier in the kernel)

    // W^T A-frags: lane holds A[m=g=16u+c][k=quad*8..+8]
    union { bf16x8 v; uint4 q; } bfr[2];
#pragma unroll
    for (int u = 0; u < 2; ++u)
        bfr[u].q = *((const uint4*)&wt[(16 * u + c) * 40 + quad * 8]);

    // swapped MFMA: D[g,l] = sum_f W[f,g] X[l,f]; sp[t] = partial score of row
    // l=16t+c over this lane's 8 g-values.
    float sp[4] = {0.f, 0.f, 0.f, 0.f};
#pragma unroll
    for (int u = 0; u < 2; ++u) {
        f32x4 a[4];
#pragma unroll
        for (int t = 0; t < 4; ++t) {
            a[t] = (f32x4){0.f, 0.f, 0.f, 0.f};
            a[t] = __builtin_amdgcn_mfma_f32_16x16x32_bf16(
                bfr[u].v, afr[t].v, a[t], 0, 0, 0);
        }
#pragma unroll
        for (int t = 0; t < 4; ++t)
#pragma unroll
            for (int r = 0; r < 4; ++r)
                sp[t] = fmaf(tanh_fast(a[t][r] + bwr[u * 4 + r]),
                             vvr[u * 4 + r], sp[t]);
    }

    // quad butterfly: all lanes get full score for their l=16t+c
    float s[4];
#pragma unroll
    for (int t = 0; t < 4; ++t) {
        float v0 = sp[t];
        v0 += __shfl_xor(v0, 16);
        v0 += __shfl_xor(v0, 32);
        s[t] = v0;
    }

    // in-register masked softmax over all 64 rows
    bool act[4];
#pragma unroll
    for (int t = 0; t < 4; ++t) act[t] = ml[t] > 0.5f;

    float m = -1e30f;
#pragma unroll
    for (int t = 0; t < 4; ++t) m = fmaxf(m, act[t] ? s[t] : -1e30f);
    m = fmaxf(m, __shfl_xor(m, 1));
    m = fmaxf(m, __shfl_xor(m, 2));
    m = fmaxf(m, __shfl_xor(m, 4));
    m = fmaxf(m, __shfl_xor(m, 8));

    float ev[4];
    float es = 0.0f;
#pragma unroll
    for (int t = 0; t < 4; ++t) {
        ev[t] = act[t] ? __expf(s[t] - m) : 0.0f;
        es += ev[t];
    }
    es += __shfl_xor(es, 1);
    es += __shfl_xor(es, 2);
    es += __shfl_xor(es, 4);
    es += __shfl_xor(es, 8);
    const float rcpS = __builtin_amdgcn_rcpf(es);

    float wgt[4];
#pragma unroll
    for (int t = 0; t < 4; ++t)
        wgt[t] = (act[t] && es > 0.0f) ? ev[t] * rcpS : 0.0f;

    // pooled[quad*8+j] = sum_l wgt[l]*X[l,f] : 4 FMA + c-butterfly per j
#pragma unroll
    for (int j = 0; j < 8; ++j) {
        float p = wgt[0] * xr[0][j];
#pragma unroll
        for (int t = 1; t < 4; ++t) p = fmaf(wgt[t], xr[t][j], p);
        p += __shfl_xor(p, 1);
        p += __shfl_xor(p, 2);
        p += __shfl_xor(p, 4);
        p += __shfl_xor(p, 8);
        if (c == 0) pool_s[w][quad * 8 + j] = p;
    }
    // wave-private buffer: drain DS queue (no block barrier)
    asm volatile("s_waitcnt lgkmcnt(0)" ::: "memory");

    // z[e] = pooled . projW[:,e] + projb[e]  (lane = e)
    float zv = pjb;
#pragma unroll
    for (int f = 0; f < 32; ++f)
        zv = fmaf(pool_s[w][f], projW[f * 64 + lane], zv);
    const bool anyl = act[0] | act[1] | act[2] | act[3];
    const bool any = (__ballot(anyl) != 0ull);
    zout[b * 64 + lane] = any ? san(zv) : 0.0f;
}

// ==================== heads: (tile, head) per block (R0, proven) =============
#define ZT 0
#define H1 4160
#define PL 0
extern "C" __global__ void __launch_bounds__(512)
heads_kernel(const float* __restrict__ z, const float* __restrict__ AM,
             const float* __restrict__ piW1, const float* __restrict__ pib1,
             const float* __restrict__ piW2, const float* __restrict__ pib2,
             const float* __restrict__ piW3, const float* __restrict__ pib3,
             const float* __restrict__ vfW1, const float* __restrict__ vfb1,
             const float* __restrict__ vfW2, const float* __restrict__ vfb2,
             const float* __restrict__ vfW3, const float* __restrict__ vfb3,
             float* __restrict__ out)
{
    __shared__ float smem[12352];

    const int tid  = threadIdx.x;
    const int w    = __builtin_amdgcn_readfirstlane(tid >> 6);
    const int el   = tid & 63;
    const bool isPi = (blockIdx.x & 1) == 0;
    const int tile  = blockIdx.x >> 1;

    for (int i = tid; i < 4096; i += 512)
        smem[ZT + (i >> 6) * 65 + (i & 63)] = z[(long)tile * 4096 + i];
    __syncthreads();

    const float* W1 = isPi ? piW1 : vfW1;
    const float* b1 = isPi ? pib1 : vfb1;
    const float* W2 = isPi ? piW2 : vfW2;
    const float* b2 = isPi ? pib2 : vfb2;

    float acc[16];
#pragma unroll
    for (int i = 0; i < 16; ++i) acc[i] = b1[w * 16 + i];
#pragma unroll 8
    for (int e = 0; e < 64; ++e) {
        const float zv = smem[ZT + el * 65 + e];
        const float* wr = W1 + e * 128 + w * 16;
#pragma unroll
        for (int i = 0; i < 16; ++i) acc[i] = fmaf(zv, wr[i], acc[i]);
    }
#pragma unroll
    for (int i = 0; i < 16; ++i)
        smem[H1 + (w * 16 + i) * 64 + el] = tanh_fast(acc[i]);
    __syncthreads();

    float a2[16];
#pragma unroll
    for (int i = 0; i < 16; ++i) a2[i] = b2[w * 16 + i];
#pragma unroll 8
    for (int j = 0; j < 128; ++j) {
        const float hv = smem[H1 + j * 64 + el];
        const float* wr = W2 + j * 128 + w * 16;
#pragma unroll
        for (int i = 0; i < 16; ++i) a2[i] = fmaf(hv, wr[i], a2[i]);
    }

    if (isPi) {
        float pl[8];
#pragma unroll
        for (int a = 0; a < 8; ++a) pl[a] = 0.0f;
#pragma unroll
        for (int i = 0; i < 16; ++i) {
            const float h2 = tanh_fast(a2[i]);
            const float* wr = piW3 + (w * 16 + i) * 8;
#pragma unroll
            for (int a = 0; a < 8; ++a) pl[a] = fmaf(h2, wr[a], pl[a]);
        }
#pragma unroll
        for (int a = 0; a < 8; ++a)
            smem[PL + w * 512 + el * 8 + a] = pl[a];
        __syncthreads();

        const int rel = tid >> 3, ra = tid & 7;
        float lg = pib3[ra];
#pragma unroll
        for (int w2 = 0; w2 < 8; ++w2)
            lg += smem[PL + w2 * 512 + rel * 8 + ra];
        lg = san(lg);
        const long rb = (long)tile * 64 + rel;
        const float am = AM[rb * 8 + ra];
        const bool inv = (am <= 0.0f);
        const unsigned long long bal = __ballot(inv);
        const int grp = (tid & 63) >> 3;
        const bool allinv = (((bal >> (grp * 8)) & 0xFFull) == 0xFFull);
        out[rb * 8 + ra] = allinv ? lg : (inv ? SAFE_NEG : lg);
    } else {
        float pv = 0.0f;
#pragma unroll
        for (int i = 0; i < 16; ++i)
            pv = fmaf(tanh_fast(a2[i]), vfW3[w * 16 + i], pv);
        smem[PL + el * 8 + w] = pv;
        __syncthreads();

        if (tid < 64) {
            float val = vfb3[0];
#pragma unroll
            for (int w2 = 0; w2 < 8; ++w2) val += smem[PL + tid * 8 + w2];
            out[(long)NBATCH * 8 + (long)tile * 64 + tid] = san(val);
        }
    }
}

// ==================== fallback: fused v4 (passed R4) =========================
extern "C" __global__ void __launch_bounds__(512, 2)
fused_v4(const float* __restrict__ X, const float* __restrict__ LM,
         const float* __restrict__ AM,
         const float* __restrict__ W, const float* __restrict__ bW,
         const float* __restrict__ vv,
         const float* __restrict__ projW, const float* __restrict__ projb,
         const float* __restrict__ piW1, const float* __restrict__ pib1,
         const float* __restrict__ piW2, const float* __restrict__ pib2,
         const float* __restrict__ piW3, const float* __restrict__ pib3,
         const float* __restrict__ vfW1, const float* __restrict__ vfb1,
         const float* __restrict__ vfW2, const float* __restrict__ vfb2,
         const float* __restrict__ vfW3, const float* __restrict__ vfb3,
         float* __restrict__ out)
{
    __shared__ __align__(16) short wt[32 * 40];
    __shared__ float zl[64 * 33];
    __shared__ float pool_s[8][32];
    __shared__ float h1pi[128 * 32];
    __shared__ float h1v[128 * 32];
    __shared__ float plpi[8 * 256];
    __shared__ float plv[32 * 8];

    const int tid  = threadIdx.x;
    const int w    = __builtin_amdgcn_readfirstlane(tid >> 6);
    const int lane = tid & 63;
    const int c    = lane & 15;
    const int quad = lane >> 4;
    const long btile = (long)blockIdx.x * 32;

    for (int i = tid; i < 1024; i += 512) {
        const int n = i >> 5, k = i & 31;
        wt[n * 40 + k] = (short)f2bf_rne(W[k * 32 + n]);
    }

    float bwr[8], vvr[8];
#pragma unroll
    for (int u = 0; u < 2; ++u)
#pragma unroll
        for (int r = 0; r < 4; ++r) {
            const int g = 16 * u + 4 * quad + r;
            bwr[u * 4 + r] = bW[g];
            vvr[u * 4 + r] = vv[g];
        }
    const float pjb = projb[lane];

    __syncthreads();

    union { bf16x8 v; uint4 q; } bfr[2];
#pragma unroll
    for (int u = 0; u < 2; ++u)
        bfr[u].q = *((const uint4*)&wt[(16 * u + c) * 40 + quad * 8]);

#pragma unroll 1
    for (int it = 0; it < 4; ++it) {
        const int brel = w * 4 + it;
        const long b = btile + brel;

        float xr[4][8];
#pragma unroll
        for (int t = 0; t < 4; ++t) {
            const float4* p = (const float4*)(X + b * 2048 + (16 * t + c) * 32 + quad * 8);
            float4 a0 = p[0], a1 = p[1];
            xr[t][0] = a0.x; xr[t][1] = a0.y; xr[t][2] = a0.z; xr[t][3] = a0.w;
            xr[t][4] = a1.x; xr[t][5] = a1.y; xr[t][6] = a1.z; xr[t][7] = a1.w;
        }
        float ml[4];
#pragma unroll
        for (int t = 0; t < 4; ++t) ml[t] = LM[b * 64 + 16 * t + c];

        union { bf16x8 v; unsigned int u[4]; } afr[4];
#pragma unroll
        for (int t = 0; t < 4; ++t)
#pragma unroll
            for (int j2 = 0; j2 < 4; ++j2)
                afr[t].u[j2] = __builtin_amdgcn_perm(
                    __float_as_uint(xr[t][2 * j2 + 1]),
                    __float_as_uint(xr[t][2 * j2]), 0x07060302u);

        float sp[4] = {0.f, 0.f, 0.f, 0.f};
#pragma unroll
        for (int u = 0; u < 2; ++u) {
            f32x4 a[4];
#pragma unroll
            for (int t = 0; t < 4; ++t) {
                a[t] = (f32x4){0.f, 0.f, 0.f, 0.f};
                a[t] = __builtin_amdgcn_mfma_f32_16x16x32_bf16(
                    bfr[u].v, afr[t].v, a[t], 0, 0, 0);
            }
#pragma unroll
            for (int t = 0; t < 4; ++t)
#pragma unroll
                for (int r = 0; r < 4; ++r)
                    sp[t] = fmaf(tanh_fast(a[t][r] + bwr[u * 4 + r]),
                                 vvr[u * 4 + r], sp[t]);
        }

        float s[4];
#pragma unroll
        for (int t = 0; t < 4; ++t) {
            float v0 = sp[t];
            v0 += __shfl_xor(v0, 16);
            v0 += __shfl_xor(v0, 32);
            s[t] = v0;
        }

        bool act[4];
#pragma unroll
        for (int t = 0; t < 4; ++t) act[t] = ml[t] > 0.5f;

        float m = -1e30f;
#pragma unroll
        for (int t = 0; t < 4; ++t) m = fmaxf(m, act[t] ? s[t] : -1e30f);
        m = fmaxf(m, __shfl_xor(m, 1));
        m = fmaxf(m, __shfl_xor(m, 2));
        m = fmaxf(m, __shfl_xor(m, 4));
        m = fmaxf(m, __shfl_xor(m, 8));

        float ev[4];
        float es = 0.0f;
#pragma unroll
        for (int t = 0; t < 4; ++t) {
            ev[t] = act[t] ? __expf(s[t] - m) : 0.0f;
            es += ev[t];
        }
        es += __shfl_xor(es, 1);
        es += __shfl_xor(es, 2);
        es += __shfl_xor(es, 4);
        es += __shfl_xor(es, 8);
        const float rcpS = __builtin_amdgcn_rcpf(es);

        float wgt[4];
#pragma unroll
        for (int t = 0; t < 4; ++t)
            wgt[t] = (act[t] && es > 0.0f) ? ev[t] * rcpS : 0.0f;

#pragma unroll
        for (int j = 0; j < 8; ++j) {
            float p = wgt[0] * xr[0][j];
#pragma unroll
            for (int t = 1; t < 4; ++t) p = fmaf(wgt[t], xr[t][j], p);
            p += __shfl_xor(p, 1);
            p += __shfl_xor(p, 2);
            p += __shfl_xor(p, 4);
            p += __shfl_xor(p, 8);
            if (c == 0) pool_s[w][quad * 8 + j] = p;
        }
        asm volatile("s_waitcnt lgkmcnt(0)" ::: "memory");

        float zv = pjb;
#pragma unroll
        for (int f = 0; f < 32; ++f)
            zv = fmaf(pool_s[w][f], projW[f * 64 + lane], zv);
        const bool anyl = act[0] | act[1] | act[2] | act[3];
        const bool any = (__ballot(anyl) != 0ull);
        zl[lane * 33 + brel] = any ? san(zv) : 0.0f;
    }
    __syncthreads();

    const int el = lane & 31;
    const int hh = lane >> 5;
    const int w4 = w - 4;

    if (w < 4) {
        const int rb0 = w * 32 + hh * 16;
        float acc[16];
#pragma unroll
        for (int i = 0; i < 16; ++i) acc[i] = pib1[rb0 + i];
#pragma unroll 8
        for (int e = 0; e < 64; ++e) {
            const float zv = zl[e * 33 + el];
            const float* wr = piW1 + e * 128 + rb0;
#pragma unroll
            for (int i = 0; i < 16; ++i) acc[i] = fmaf(zv, wr[i], acc[i]);
        }
#pragma unroll
        for (int i = 0; i < 16; ++i)
            h1pi[(rb0 + i) * 32 + el] = tanh_fast(acc[i]);
    } else {
        const int rb0 = w4 * 32 + hh * 16;
        float acc[16];
#pragma unroll
        for (int i = 0; i < 16; ++i) acc[i] = vfb1[rb0 + i];
#pragma unroll 8
        for (int e = 0; e < 64; ++e) {
            const float zv = zl[e * 33 + el];
            const float* wr = vfW1 + e * 128 + rb0;
#pragma unroll
            for (int i = 0; i < 16; ++i) acc[i] = fmaf(zv, wr[i], acc[i]);
        }
#pragma unroll
        for (int i = 0; i < 16; ++i)
            h1v[(rb0 + i) * 32 + el] = tanh_fast(acc[i]);
    }
    __syncthreads();

    if (w < 4) {
        const int rb0 = w * 32 + hh * 16;
        const int g   = w * 2 + hh;
        float a2[16];
#pragma unroll
        for (int i = 0; i < 16; ++i) a2[i] = pib2[rb0 + i];
#pragma unroll 8
        for (int j = 0; j < 128; ++j) {
            const float hv = h1pi[j * 32 + el];
            const float* wr = piW2 + j * 128 + rb0;
#pragma unroll
            for (int i = 0; i < 16; ++i) a2[i] = fmaf(hv, wr[i], a2[i]);
        }
        float pl[8];
#pragma unroll
        for (int a = 0; a < 8; ++a) pl[a] = 0.0f;
#pragma unroll
        for (int i = 0; i < 16; ++i) {
            const float h2 = tanh_fast(a2[i]);
            const float* wr = piW3 + (rb0 + i) * 8;
#pragma unroll
            for (int a = 0; a < 8; ++a) pl[a] = fmaf(h2, wr[a], pl[a]);
        }
#pragma unroll
        for (int a = 0; a < 8; ++a)
            plpi[g * 256 + el * 8 + a] = pl[a];
    } else {
        const int rb0 = w4 * 32 + hh * 16;
        const int g   = w4 * 2 + hh;
        float a2[16];
#pragma unroll
        for (int i = 0; i < 16; ++i) a2[i] = vfb2[rb0 + i];
#pragma unroll 8
        for (int j = 0; j < 128; ++j) {
            const float hv = h1v[j * 32 + el];
            const float* wr = vfW2 + j * 128 + rb0;
#pragma unroll
            for (int i = 0; i < 16; ++i) a2[i] = fmaf(hv, wr[i], a2[i]);
        }
        float pv = 0.0f;
#pragma unroll
        for (int i = 0; i < 16; ++i)
            pv = fmaf(tanh_fast(a2[i]), vfW3[rb0 + i], pv);
        plv[el * 8 + g] = pv;
    }
    __syncthreads();

    if (w < 4) {
        const int rel = tid >> 3, ra = tid & 7;
        float lg = pib3[ra];
#pragma unroll
        for (int g2 = 0; g2 < 8; ++g2)
            lg += plpi[g2 * 256 + rel * 8 + ra];
        lg = san(lg);
        const long rb = btile + rel;
        const float am = AM[rb * 8 + ra];
        const bool inv = (am <= 0.0f);
        const unsigned long long bal = __ballot(inv);
        const int grp = (tid & 63) >> 3;
        const bool allinv = (((bal >> (grp * 8)) & 0xFFull) == 0xFFull);
        out[rb * 8 + ra] = allinv ? lg : (inv ? SAFE_NEG : lg);
    } else if (w == 4) {
        if (lane < 32) {
            float val = vfb3[0];
#pragma unroll
            for (int g2 = 0; g2 < 8; ++g2) val += plv[lane * 8 + g2];
            out[(long)NBATCH * 8 + btile + lane] = san(val);
        }
    }
}

// ---------------- launcher ----------------
extern "C" void kernel_launch(void* const* d_in, const int* in_sizes, int n_in,
                              void* d_out, int out_size, void* d_ws, size_t ws_size,
                              hipStream_t stream) {
    const float* X     = (const float*)d_in[0];
    const float* LM    = (const float*)d_in[1];
    const float* AM    = (const float*)d_in[2];
    const float* W     = (const float*)d_in[3];
    const float* bW    = (const float*)d_in[4];
    const float* vv    = (const float*)d_in[5];
    const float* projW = (const float*)d_in[6];
    const float* projb = (const float*)d_in[7];
    const float* piW1  = (const float*)d_in[8];
    const float* pib1  = (const float*)d_in[9];
    const float* piW2  = (const float*)d_in[10];
    const float* pib2  = (const float*)d_in[11];
    const float* piW3  = (const float*)d_in[12];
    const float* pib3  = (const float*)d_in[13];
    const float* vfW1  = (const float*)d_in[14];
    const float* vfb1  = (const float*)d_in[15];
    const float* vfW2  = (const float*)d_in[16];
    const float* vfb2  = (const float*)d_in[17];
    const float* vfW3  = (const float*)d_in[18];
    const float* vfb3  = (const float*)d_in[19];

    float* outp = (float*)d_out;
    const size_t zbytes = (size_t)NBATCH * 64 * sizeof(float);

    if (ws_size >= zbytes) {
        float* z = (float*)d_ws;
        pool_v5<<<NBATCH / 4, 256, 0, stream>>>(
            X, LM, W, bW, vv, projW, projb, z);
        heads_kernel<<<(NBATCH / 64) * 2, 512, 0, stream>>>(
            z, AM, piW1, pib1, piW2, pib2, piW3, pib3,
            vfW1, vfb1, vfW2, vfb2, vfW3, vfb3, outp);
    } else {
        fused_v4<<<NBATCH / 32, 512, 0, stream>>>(
            X, LM, AM, W, bW, vv, projW, projb,
            piW1, pib1, piW2, pib2, piW3, pib3,
            vfW1, vfb1, vfW2, vfb2, vfW3, vfb3, outp);
    }
}